// Round 1
// 85.778 us; speedup vs baseline: 1.0421x; 1.0421x over previous
//
#include <hip/hip_runtime.h>
#include <math.h>

#define PI_F 3.14159265358979323846f
#define WARM_Y 12          // warm-up years: 0.907^144 * 0.56 ~ 4e-7 residual in M
#define BY 64              // years per block (one wave of chains)
#define BS 256             // threads per block (4 waves)
#define NGRP (BY + WARM_Y) // 76 year-groups staged per block
#define NPAD (NGRP * 13)   // padded LDS floats (stride 13 -> conflict-free)

// Hardware log2/exp2 (v_log_f32/v_exp_f32). Args >= 0 here; 0 -> -inf -> 0 = pow(0,y).
#if __has_builtin(__builtin_amdgcn_logf) && __has_builtin(__builtin_amdgcn_exp2f)
__device__ __forceinline__ float flog2(float x) { return __builtin_amdgcn_logf(x); }
__device__ __forceinline__ float fexp2(float x) { return __builtin_amdgcn_exp2f(x); }
#else
__device__ __forceinline__ float flog2(float x) { return log2f(x); }
__device__ __forceinline__ float fexp2(float x) { return exp2f(x); }
#endif
__device__ __forceinline__ float fpow(float x, float y) { return fexp2(y * flog2(x)); }

__constant__ int   c_CDAYS[13]  = {0,31,59,90,120,151,181,212,243,273,304,334,365};
__constant__ float c_NDAYSF[13] = {0,31,28,31,30,31,30,31,31,30,31,30,31};

#define POW_C 1.9345076f   // 4.886 * log2(1/0.76): folds frac=M/0.76 into the exponent

// One fused kernel: insolation + PET + contractive soil scan + last-block z-score.
// ws layout: [0..3] counter (memset to 0 each launch), [16..] 2 doubles per block.
//
// Phase plan (waves are disjoint workers; 6 barriers total vs 14 before):
//   P0: stage T/P -> LDS, daily dtsi, sL (wave2 lanes 0-11)
//   P1: PET (tids 0-75) || day-max via shfl (wave2) || monthly dtsi sums (wave3)
//   P2: gE (tids 64-75)
//   P3: chain (wave0) + wave-reduce partials
//   epilogue: last-block z-score (float4)
__global__ void k_all(const int* __restrict__ phi_ptr,
                      const float* __restrict__ T, const float* __restrict__ P,
                      const float* __restrict__ T1p, const float* __restrict__ T2p,
                      const float* __restrict__ M1p, const float* __restrict__ M2p,
                      float* out, unsigned int* ctr, double* partials, int nyrs) {
    __shared__ float sA[NPAD];
    __shared__ float sB[NPAD];
    __shared__ float sT[NPAD];
    __shared__ float dtsi[365];
    __shared__ float sL[12], sGE[12], sGEsum[12];
    __shared__ float sMaxd;
    __shared__ int   is_last_s;
    __shared__ float mean_s, inv_s;

    const int tid = threadIdx.x;
    const float latr = (float)(*phi_ptr) * (PI_F / 180.f);
    const float tl = tanf(latr), slat = sinf(latr), clat = cosf(latr);

    // ---- P0: insolation daily curve (identical per block; 2 rounds at BS=256) ----
    for (int d = tid; d < 365; d += BS) {
        float jd = (float)(d + 1);
        float sd = asinf(sinf(PI_F * 23.5f / 180.f) * sinf(PI_F * (jd - 80.f) / 180.f));
        float y  = fminf(1.f, fmaxf(-1.f, -tl * tanf(sd)));
        float hdl = acosf(y);
        dtsi[d] = hdl * slat * sinf(sd) + clat * cosf(sd) * sinf(hdl);
    }

    // ---- P0: stage T, P (B = P/1000); out-of-range groups become identity steps ----
    const int nmon = nyrs * 12;
    const int base = (blockIdx.x * BY - WARM_Y) * 12;
    for (int t = tid; t < NGRP * 12; t += BS) {
        int tg = base + t;
        int pt = t + t / 12;                 // g*13 + m
        float p = 0.f, tt = 0.f;
        if (tg >= 0 && tg < nmon) { p = P[tg]; tt = T[tg]; }
        sB[pt] = p * 1e-3f;
        sT[pt] = tt;
    }

    // ---- P0: monthly day-length factor sL (wave 2, lanes 0-11; needs only tl) ----
    if (tid >= 128 && tid < 140) {
        int m = tid - 128;
        float nd = c_NDAYSF[m + 1];
        float jm = (float)c_CDAYS[m] + 0.5f * nd;
        float ms = 1.f - tl * tanf(23.439f * PI_F / 180.f * cosf(jm * PI_F / 182.625f));
        ms = fminf(2.f, fmaxf(0.f, ms));
        float nhrs = 24.f * acosf(1.f - ms) / PI_F;
        sL[m] = nd / 30.f * (nhrs / 12.f);
    }
    __syncthreads();                                   // (1)

    // ---- P1a: PET -> linear coefficient A per staged year-group (tids 0-75) ----
    if (tid < NGRP) {
        int g = tid;
        int yg = blockIdx.x * BY - WARM_Y + g;
        int pt = g * 13;
        if (yg < 0 || yg >= nyrs) {
#pragma unroll
            for (int m = 0; m < 12; ++m) sA[pt + m] = 1.f;   // identity (B==0)
        } else {
            float I = 0.f;
#pragma unroll
            for (int m = 0; m < 12; ++m) {
                float is = fmaxf(sT[pt + m] * 0.2f, 0.f);
                I += fpow(is, 1.514f);
            }
            float a  = 6.75e-07f * I * I * I - 7.71e-05f * I * I + 0.0179f * I + 0.49f;
            float rI = 10.0f / I;
#pragma unroll
            for (int m = 0; m < 12; ++m) {
                float t = sT[pt + m];
                float ep;
                if (t < 0.f)          ep = 0.f;
                else if (t < 26.5f)   ep = 16.f * sL[m] * fpow(t * rI, a);
                else                  ep = -415.85f + 32.25f * t - 0.43f * t * t;
                sA[pt + m] = (1.0f - 0.093f) - ep * (1.0f / 760.0f);
            }
        }
    }

    // ---- P1b: max(dtsi) on wave 2 via shuffles (no barrier tree) ----
    if (tid >= 128 && tid < 192) {
        float mx = -1e30f;
        for (int d = tid - 128; d < 365; d += 64) mx = fmaxf(mx, dtsi[d]);
#pragma unroll
        for (int off = 32; off > 0; off >>= 1) mx = fmaxf(mx, __shfl_xor(mx, off));
        if (tid == 128) sMaxd = mx;
    }

    // ---- P1c: monthly dtsi sums on wave 3 (lanes 0-11) ----
    if (tid >= 192 && tid < 204) {
        int m = tid - 192;
        int c0 = c_CDAYS[m], c1 = c_CDAYS[m + 1];
        float s = 0.f;
        for (int i = c0; i < c1; ++i) s += dtsi[i];
        sGEsum[m] = s;
    }
    __syncthreads();                                   // (2)

    // ---- P2: gE = monthly mean / max (tids 64-75) ----
    if (tid >= 64 && tid < 76) {
        int m = tid - 64;
        int c0 = c_CDAYS[m], c1 = c_CDAYS[m + 1];
        sGE[m] = (sGEsum[m] / (float)(c1 - c0)) / sMaxd;
    }
    __syncthreads();                                   // (3)

    // ---- P3: wave 0 per-thread chain (12 warm-up years + 1 real year) ----
    double wsum = 0.0, wsq = 0.0;
    if (tid < BY) {
        const float T1 = *T1p, T2 = *T2p, M1 = *M1p, M2 = *M2p;
        const int ly = tid;
        const int y = blockIdx.x * BY + ly;
        const float invT = 1.0f / (T2 - T1);
        const float invM = 1.0f / (M2 - M1);
        float M = 0.2f;
        for (int g = ly; g < ly + WARM_Y; ++g) {     // identity groups make M0 exact
            int pt = g * 13;
#pragma unroll
            for (int m = 0; m < 12; ++m) {
                float a = sA[pt + m], b = sB[pt + m];
                float pw = fexp2(fmaf(4.886f, flog2(M), POW_C));   // (M/0.76)^4.886
                float K = fmaf(a, M, b);
                M = fmaf(-b, pw, K);
                M = fminf(0.76f, fmaxf(0.01f, M));
            }
        }
        float acc = 0.f;
        {
            int pt = (ly + WARM_Y) * 13;
#pragma unroll
            for (int m = 0; m < 12; ++m) {
                float a = sA[pt + m], b = sB[pt + m];
                float pw = fexp2(fmaf(4.886f, flog2(M), POW_C));
                float K = fmaf(a, M, b);
                M = fmaf(-b, pw, K);
                M = fminf(0.76f, fmaxf(0.01f, M));
                float gT = fminf(fmaxf((sT[pt + m] - T1) * invT, 0.f), 1.f);
                float gM = fminf(fmaxf((M - M1) * invM, 0.f), 1.f);
                acc += fminf(gT, gM) * sGE[m];
            }
        }
        if (y < nyrs) {
            out[y] = acc;
            wsum = (double)acc;
            wsq  = (double)acc * (double)acc;
        }
        // wave-level reduction of (sum, sumsq) across 64 lanes
        for (int off = 32; off > 0; off >>= 1) {
            wsum += __shfl_down(wsum, off);
            wsq  += __shfl_down(wsq,  off);
        }
        if (ly == 0) {
            partials[2 * blockIdx.x]     = wsum;
            partials[2 * blockIdx.x + 1] = wsq;
        }
    }
    __syncthreads();                                   // (4)

    // ---- last-block-done: z-score normalize in place ----
    if (tid == 0) {
        __threadfence();                                  // release width+partials
        unsigned int old = atomicAdd(ctr, 1u);            // device-scope by default
        is_last_s = (old == gridDim.x - 1) ? 1 : 0;
    }
    __syncthreads();                                   // (5)
    if (!is_last_s) return;
    __threadfence();                                      // acquire others' writes

    if (tid < 64) {
        const int nb = gridDim.x;
        double sm = 0.0, sq = 0.0;
        for (int b = tid; b < nb; b += 64) {
            sm += partials[2 * b];
            sq += partials[2 * b + 1];
        }
        for (int off = 32; off > 0; off >>= 1) {
            sm += __shfl_down(sm, off);
            sq += __shfl_down(sq, off);
        }
        if (tid == 0) {
            double mean = sm / (double)nyrs;
            double var  = (sq - (double)nyrs * mean * mean) / (double)(nyrs - 1);
            mean_s = (float)mean;
            inv_s  = (float)(1.0 / sqrt(var));
        }
    }
    __syncthreads();                                   // (6)
    {
        const float mean = mean_s, inv = inv_s;
        const int n4 = nyrs >> 2;
        float4* o4 = (float4*)out;
        for (int i = tid; i < n4; i += BS) {
            float4 v = o4[i];
            v.x = (v.x - mean) * inv;
            v.y = (v.y - mean) * inv;
            v.z = (v.z - mean) * inv;
            v.w = (v.w - mean) * inv;
            o4[i] = v;
        }
        for (int i = (n4 << 2) + tid; i < nyrs; i += BS)
            out[i] = (out[i] - mean) * inv;
    }
}

extern "C" void kernel_launch(void* const* d_in, const int* in_sizes, int n_in,
                              void* d_out, int out_size, void* d_ws, size_t ws_size,
                              hipStream_t stream) {
    // inputs: 0=syear 1=eyear 2=phi(int) 3=T(f32) 4=P(f32) 5=T1 6=T2 7=M1 8=M2
    const int*   phi = (const int*)d_in[2];
    const float* T   = (const float*)d_in[3];
    const float* P   = (const float*)d_in[4];
    const float* T1  = (const float*)d_in[5];
    const float* T2  = (const float*)d_in[6];
    const float* M1  = (const float*)d_in[7];
    const float* M2  = (const float*)d_in[8];
    float* out = (float*)d_out;

    const int nyrs = in_sizes[3] / 12;   // 8192
    const int nblk = (nyrs + BY - 1) / BY;

    unsigned int* ctr = (unsigned int*)d_ws;                     // 4 B, zeroed below
    double* partials  = (double*)((char*)d_ws + 16);             // 2 doubles / block

    hipMemsetAsync(ctr, 0, sizeof(unsigned int), stream);        // capturable node
    k_all<<<nblk, BS, 0, stream>>>(phi, T, P, T1, T2, M1, M2, out, ctr, partials, nyrs);
}